// Round 1
// baseline (15564.075 us; speedup 1.0000x reference)
//
#include <hip/hip_runtime.h>
#include <hip/hip_bf16.h>

// Problem constants (match reference)
#define Tn 2048
#define Bn 32
#define Dn 256
#define Un 256
// 4U = 1024 gate columns, split as [i|f|g|o] blocks of 256.

using short8 = __attribute__((ext_vector_type(8))) short;
using f32x4  = __attribute__((ext_vector_type(4))) float;

__device__ __forceinline__ unsigned short f2bf(float f) {
    unsigned int u = __builtin_bit_cast(unsigned int, f);
    u += 0x7fffu + ((u >> 16) & 1u);   // round-to-nearest-even
    return (unsigned short)(u >> 16);
}
__device__ __forceinline__ float bf2f(unsigned short v) {
    unsigned int u = ((unsigned int)v) << 16;
    return __builtin_bit_cast(float, u);
}
__device__ __forceinline__ float sigm(float x)   { return 1.0f / (1.0f + __expf(-x)); }
__device__ __forceinline__ float tanh_f(float x) { return 1.0f - 2.0f / (__expf(2.0f * x) + 1.0f); }

// ---------------------------------------------------------------------------
// Kernel 1: zx = data @ Wx, stored as bf16, layout [T][B][1024] (t-major so the
// recurrent kernel reads contiguous rows per step). Bias added later in gates.
// Tile 128x128, BK=32, 512 threads (8 waves = 2m x 4n), bf16 MFMA 16x16x32.
// A-fragments loaded directly from global fp32 (L1-cached), B staged via LDS
// transposed+converted.
// ---------------------------------------------------------------------------
__global__ __launch_bounds__(512) void gemm_zx(const float* __restrict__ data,
                                               const float* __restrict__ Wx,
                                               unsigned short* __restrict__ zws)
{
    __shared__ unsigned short BsubT[128 * 40];   // [col][k] pad 40 (80B stride, 16B-aligned)

    const int bid = blockIdx.x;
    const int bn = bid & 7;      // 8 n-tiles of 128
    const int bm = bid >> 3;     // 512 m-tiles of 128
    const int tid = threadIdx.x;
    const int lane = tid & 63, wid = tid >> 6;
    const int wm = wid >> 2, wn = wid & 3;       // 2 x 4 wave grid
    const int l15 = lane & 15, lk = lane >> 4;   // lk in 0..3

    f32x4 acc[4][2];
    #pragma unroll
    for (int mt = 0; mt < 4; ++mt)
        #pragma unroll
        for (int nt = 0; nt < 2; ++nt)
            acc[mt][nt] = f32x4{0.f, 0.f, 0.f, 0.f};

    const int colStage = tid & 127;
    const int kqStage  = tid >> 7;   // 0..3

    for (int ks = 0; ks < 8; ++ks) {
        __syncthreads();
        // stage B tile [32k x 128col] -> BsubT[col][k] (bf16)
        {
            const float* wp = Wx + (size_t)(ks * 32 + kqStage) * 1024 + bn * 128 + colStage;
            #pragma unroll
            for (int kk = 0; kk < 8; ++kk) {
                float v = wp[(size_t)kk * 4 * 1024];          // k-local = kqStage + kk*4
                BsubT[colStage * 40 + (kqStage + kk * 4)] = f2bf(v);
            }
        }
        __syncthreads();

        // A fragments: direct global fp32 -> bf16
        short8 afr[4];
        #pragma unroll
        for (int mt = 0; mt < 4; ++mt) {
            int row = bm * 128 + wm * 64 + mt * 16 + l15;
            const float* ap = data + (size_t)row * 256 + ks * 32 + lk * 8;
            float4 a0 = *(const float4*)(ap);
            float4 a1 = *(const float4*)(ap + 4);
            short8 a;
            a[0] = (short)f2bf(a0.x); a[1] = (short)f2bf(a0.y);
            a[2] = (short)f2bf(a0.z); a[3] = (short)f2bf(a0.w);
            a[4] = (short)f2bf(a1.x); a[5] = (short)f2bf(a1.y);
            a[6] = (short)f2bf(a1.z); a[7] = (short)f2bf(a1.w);
            afr[mt] = a;
        }
        #pragma unroll
        for (int nt = 0; nt < 2; ++nt) {
            int colL = wn * 32 + nt * 16 + l15;
            short8 bfr = *(const short8*)&BsubT[colL * 40 + lk * 8];
            #pragma unroll
            for (int mt = 0; mt < 4; ++mt)
                acc[mt][nt] = __builtin_amdgcn_mfma_f32_16x16x32_bf16(afr[mt], bfr, acc[mt][nt], 0, 0, 0);
        }
    }

    // epilogue: row = b*T + t  ->  zws[(t*B + b)*1024 + col]
    #pragma unroll
    for (int mt = 0; mt < 4; ++mt) {
        #pragma unroll
        for (int nt = 0; nt < 2; ++nt) {
            int col = bn * 128 + wn * 32 + nt * 16 + l15;
            #pragma unroll
            for (int r = 0; r < 4; ++r) {
                int row = bm * 128 + wm * 64 + mt * 16 + lk * 4 + r;
                int b_ = row >> 11;          // /2048
                int t_ = row & 2047;
                zws[(size_t)(t_ * 32 + b_) * 1024 + col] = f2bf(acc[mt][nt][r]);
            }
        }
    }
}

// ---------------------------------------------------------------------------
// Kernel 2: the recurrence. 16 worker blocks (bid%8==0 -> XCD-colocation
// heuristic), each owns a 16-u column chunk of Wh (64 gate-cols, bf16, LDS)
// and all 32 batches. Per step: MFMA [32,256]@[256,64] with h read directly
// from the global exchange buffer, gate math, h written back + flag release.
// ---------------------------------------------------------------------------
#define NBLK 16

__global__ __launch_bounds__(512) void lstm_rec(const float* __restrict__ Wh,
                                                const float* __restrict__ bias,
                                                const unsigned short* __restrict__ zws,
                                                unsigned short* __restrict__ hG,   // [2][32][256] bf16
                                                unsigned int* __restrict__ flags,  // [T]
                                                float* __restrict__ out)           // [B][T][U] f32
{
    const int bid = blockIdx.x;
    if ((bid & 7) != 0) return;          // XCD-colocation heuristic (perf only)
    const int chunk = bid >> 3;          // 0..15
    if (chunk >= NBLK) return;

    __shared__ unsigned short whcT[64 * 256];  // [col][k] bf16, XOR-swizzled, 32KB
    __shared__ float zbuf[64 * 33];            // [col][batch] fp32, padded

    const int tid = threadIdx.x;
    const int lane = tid & 63, wid = tid >> 6;     // 8 waves
    const int mt = wid >> 2, nt = wid & 3;         // (m-tile 0..1, gate 0..3)
    const int l15 = lane & 15, lk = lane >> 4;

    // ---- one-time: stage Wh chunk (fp32 global -> bf16 LDS, transposed+swizzled)
    {
        const int c  = tid & 63;          // local col: gate g = c>>4, j = c&15
        const int kq = tid >> 6;          // 0..7
        const int g  = c >> 4, j = c & 15;
        const int colg = g * 256 + chunk * 16 + j;
        for (int kk = 0; kk < 32; ++kk) {
            int k = kq * 32 + kk;
            unsigned short v = f2bf(Wh[(size_t)k * 1024 + colg]);
            int byte = c * 512 + ((k * 2) ^ ((c & 7) << 4));
            *(unsigned short*)((char*)whcT + byte) = v;
        }
    }

    // ---- gate-phase identity: thread <-> (u, batch)
    const int u  = tid & 15;
    const int bb = tid >> 4;              // 0..31
    const int ug = chunk * 16 + u;        // global u

    float bias_r[4];
    #pragma unroll
    for (int g4 = 0; g4 < 4; ++g4) bias_r[g4] = bias[g4 * 256 + ug];

    float c_state = 0.0f;

    // prefetch zx for t=0
    unsigned short zx_pf[4];
    #pragma unroll
    for (int g4 = 0; g4 < 4; ++g4)
        zx_pf[g4] = zws[(size_t)(0 * 32 + bb) * 1024 + g4 * 256 + ug];

    __syncthreads();   // whcT ready

    for (int t = 0; t < Tn; ++t) {
        f32x4 acc = f32x4{0.f, 0.f, 0.f, 0.f};

        if (t > 0) {
            if (tid == 0) {
                while (__hip_atomic_load(&flags[t - 1], __ATOMIC_ACQUIRE, __HIP_MEMORY_SCOPE_AGENT) < NBLK)
                    __builtin_amdgcn_s_sleep(2);
            }
            __syncthreads();   // everyone sees h(t-1); L1 invalidated by acquire

            const unsigned short* hp = hG + (size_t)((t - 1) & 1) * (32 * 256);
            const int row  = mt * 16 + l15;
            const int colL = nt * 16 + l15;
            #pragma unroll
            for (int ks = 0; ks < 8; ++ks) {
                int k0 = ks * 32 + lk * 8;
                short8 afr = *(const short8*)(hp + (size_t)row * 256 + k0);
                int byte = colL * 512 + ((k0 * 2) ^ ((colL & 7) << 4));
                short8 bfr = *(const short8*)((const char*)whcT + byte);
                acc = __builtin_amdgcn_mfma_f32_16x16x32_bf16(afr, bfr, acc, 0, 0, 0);
            }
        }

        // write z-partial to zbuf: C layout col=lane&15, row=(lane>>4)*4+reg
        {
            const int colL = nt * 16 + l15;
            #pragma unroll
            for (int r = 0; r < 4; ++r) {
                int brow = mt * 16 + lk * 4 + r;
                zbuf[colL * 33 + brow] = acc[r];
            }
        }
        __syncthreads();

        // gate phase
        float zi = zbuf[(0 * 16 + u) * 33 + bb] + bf2f(zx_pf[0]) + bias_r[0];
        float zf = zbuf[(1 * 16 + u) * 33 + bb] + bf2f(zx_pf[1]) + bias_r[1];
        float zg = zbuf[(2 * 16 + u) * 33 + bb] + bf2f(zx_pf[2]) + bias_r[2];
        float zo = zbuf[(3 * 16 + u) * 33 + bb] + bf2f(zx_pf[3]) + bias_r[3];

        float ig = sigm(zi), fg = sigm(zf), gg = tanh_f(zg), og = sigm(zo);
        c_state = fg * c_state + ig * gg;
        float h = og * tanh_f(c_state);

        out[((size_t)bb * Tn + t) * Un + ug] = h;
        hG[(size_t)(t & 1) * (32 * 256) + bb * 256 + ug] = f2bf(h);

        // prefetch zx for t+1 (full step of latency to hide HBM)
        if (t + 1 < Tn) {
            #pragma unroll
            for (int g4 = 0; g4 < 4; ++g4)
                zx_pf[g4] = zws[(size_t)((t + 1) * 32 + bb) * 1024 + g4 * 256 + ug];
        }

        __syncthreads();   // all h-writes done before the release
        if (tid == 0) {
            __threadfence();   // agent-scope: make block's h stores visible
            __hip_atomic_fetch_add(&flags[t], 1u, __ATOMIC_RELEASE, __HIP_MEMORY_SCOPE_AGENT);
        }
    }
}

// ---------------------------------------------------------------------------
extern "C" void kernel_launch(void* const* d_in, const int* in_sizes, int n_in,
                              void* d_out, int out_size, void* d_ws, size_t ws_size,
                              hipStream_t stream)
{
    const float* data = (const float*)d_in[0];   // [32,2048,256]
    const float* Wx   = (const float*)d_in[1];   // [256,1024]
    const float* Wh   = (const float*)d_in[2];   // [256,1024]
    const float* bias = (const float*)d_in[3];   // [1024]
    float* out = (float*)d_out;

    char* ws = (char*)d_ws;
    unsigned short* zws = (unsigned short*)ws;                       // 128 MB: [T][B][1024] bf16
    size_t zbytes = (size_t)Tn * Bn * 1024 * 2;
    unsigned short* hG = (unsigned short*)(ws + zbytes);             // 32 KB
    unsigned int* flags = (unsigned int*)(ws + zbytes + 2 * 32 * 256 * 2);  // 8 KB

    hipMemsetAsync(flags, 0, Tn * sizeof(unsigned int), stream);

    gemm_zx<<<dim3(4096), dim3(512), 0, stream>>>(data, Wx, zws);

    // 128 blocks; only bid%8==0 work -> 16 workers, ideally all on XCD0
    lstm_rec<<<dim3(128), dim3(512), 0, stream>>>(Wh, bias, zws, hG, flags, out);
}